// Round 3
// baseline (892.762 us; speedup 1.0000x reference)
//
#include <hip/hip_runtime.h>

typedef __attribute__((ext_vector_type(8))) _Float16 f16x8;
typedef __attribute__((ext_vector_type(4))) _Float16 f16x4;
typedef __attribute__((ext_vector_type(4))) float f32x4;

#define NB 4
#define NS 4096
#define NE 512

__device__ __forceinline__ f16x8 cvt2(float4 a, float4 b) {
    f16x8 r;
    r[0] = (_Float16)a.x; r[1] = (_Float16)a.y; r[2] = (_Float16)a.z; r[3] = (_Float16)a.w;
    r[4] = (_Float16)b.x; r[5] = (_Float16)b.y; r[6] = (_Float16)b.z; r[7] = (_Float16)b.w;
    return r;
}

// ---------------- Stage 1: fused QKV projection (fp32 in, f16 out) ------
// out = X @ W^T + b. X:[nb*4096,512] fp32 (chunk at batch b0), W:[512,512] fp32.
// which=0: q (chunk-relative rows, f16)  which=1: k (same)  which=2: v -> [b_rel][d][s]
__global__ __launch_bounds__(256) void proj_kernel(
    const float* __restrict__ Xq, const float* __restrict__ Xk,
    const float* __restrict__ Xv,
    const float* __restrict__ Wq, const float* __restrict__ Wk,
    const float* __restrict__ Wv,
    const float* __restrict__ bq, const float* __restrict__ bk,
    const float* __restrict__ bv,
    _Float16* __restrict__ oq, _Float16* __restrict__ ok,
    _Float16* __restrict__ ovt, int b0)
{
    __shared__ __align__(16) _Float16 As[128 * 32];
    __shared__ __align__(16) _Float16 Bs[128 * 32];
    const int t = threadIdx.x;
    const int w = t >> 6, ln = t & 63;
    const int which = blockIdx.y;
    const float* X    = (which == 0) ? Xq : ((which == 1) ? Xk : Xv);
    const float* W    = (which == 0) ? Wq : ((which == 1) ? Wk : Wv);
    const float* bias = (which == 0) ? bq : ((which == 1) ? bk : bv);

    const int m0 = (blockIdx.x >> 2) * 128;   // chunk-relative row block
    const int n0 = (blockIdx.x & 3) * 128;

    // staging: thread t covers tile row t>>1, float cols (t&1)*16 .. +16
    const int srow  = t >> 1;
    const int shalf = (t & 1) * 16;
    const float* gA = X + ((size_t)b0 * NS + m0 + srow) * NE + shalf;
    const float* gB = W + (size_t)(n0 + srow) * NE + shalf;
    _Float16* lA = &As[srow * 32 + shalf];
    _Float16* lB = &Bs[srow * 32 + shalf];

    f32x4 acc[4][4] = {};
    const int wm = (w >> 1) * 64, wn = (w & 1) * 64;
    const int lcol = ln & 15, lq = ln >> 4;

    for (int k0 = 0; k0 < NE; k0 += 32) {
        float4 xa0 = *(const float4*)(gA + k0);
        float4 xa1 = *(const float4*)(gA + k0 + 4);
        float4 xa2 = *(const float4*)(gA + k0 + 8);
        float4 xa3 = *(const float4*)(gA + k0 + 12);
        float4 xb0 = *(const float4*)(gB + k0);
        float4 xb1 = *(const float4*)(gB + k0 + 4);
        float4 xb2 = *(const float4*)(gB + k0 + 8);
        float4 xb3 = *(const float4*)(gB + k0 + 12);
        __syncthreads();
        *(f16x8*)lA       = cvt2(xa0, xa1);
        *(f16x8*)(lA + 8) = cvt2(xa2, xa3);
        *(f16x8*)lB       = cvt2(xb0, xb1);
        *(f16x8*)(lB + 8) = cvt2(xb2, xb3);
        __syncthreads();
        f16x8 a[4], b[4];
#pragma unroll
        for (int i = 0; i < 4; i++)
            a[i] = *(const f16x8*)&As[(wm + i * 16 + lcol) * 32 + lq * 8];
#pragma unroll
        for (int j = 0; j < 4; j++)
            b[j] = *(const f16x8*)&Bs[(wn + j * 16 + lcol) * 32 + lq * 8];
#pragma unroll
        for (int i = 0; i < 4; i++)
#pragma unroll
            for (int j = 0; j < 4; j++)
                acc[i][j] = __builtin_amdgcn_mfma_f32_16x16x32_f16(a[i], b[j], acc[i][j], 0, 0, 0);
    }

    // C/D layout: col = lane&15, row = (lane>>4)*4 + reg
    if (which < 2) {
        _Float16* o = (which == 0) ? oq : ok;
#pragma unroll
        for (int j = 0; j < 4; j++) {
            const int col = n0 + wn + j * 16 + lcol;
            const float bb = bias[col];
#pragma unroll
            for (int i = 0; i < 4; i++) {
                const int rbase = m0 + wm + i * 16 + lq * 4;
#pragma unroll
                for (int r = 0; r < 4; r++)
                    o[(size_t)(rbase + r) * NE + col] = (_Float16)(acc[i][j][r] + bb);
            }
        }
    } else {
#pragma unroll
        for (int j = 0; j < 4; j++) {
            const int d = n0 + wn + j * 16 + lcol;
            const float bb = bias[d];
#pragma unroll
            for (int i = 0; i < 4; i++) {
                const int rbase = m0 + wm + i * 16 + lq * 4;
                const int bat = rbase >> 12;           // chunk-relative batch
                const int s   = rbase & 4095;
                f16x4 pk;
#pragma unroll
                for (int r = 0; r < 4; r++) pk[r] = (_Float16)(acc[i][j][r] + bb);
                *(f16x4*)&ovt[((size_t)bat * NE + d) * NS + s] = pk;
            }
        }
    }
}

// ---------------- Stage 2: flash attention (f16 in, fp32 out) -----------
// grid (S/64, nb). q/k/vt chunk-relative f16 in ws; out absolute fp32 rows.
__global__ __launch_bounds__(256) void attn_kernel(
    const _Float16* __restrict__ q, const _Float16* __restrict__ k,
    const _Float16* __restrict__ vt, float* __restrict__ out, int b0)
{
    __shared__ __align__(16) _Float16 Ks[32 * 520];
    __shared__ __align__(16) _Float16 Vs[512 * 40];
    __shared__ __align__(16) _Float16 Ps[4][16 * 40];
    const int t = threadIdx.x, w = t >> 6, ln = t & 63;
    const int lcol = ln & 15, lq = ln >> 4;
    const int rel = blockIdx.y;          // chunk-relative batch
    const int babs = b0 + rel;           // absolute batch (out only)
    const int q0 = blockIdx.x * 64;

    const _Float16* qp = q + ((size_t)rel * NS + q0 + w * 16 + lcol) * NE + lq * 8;
    f16x8 qf[16];
#pragma unroll
    for (int ks = 0; ks < 16; ks++) qf[ks] = *(const f16x8*)(qp + ks * 32);

    const _Float16* kg = k + (size_t)rel * NS * NE;
    const _Float16* vg = vt + (size_t)rel * NE * NS;

    f32x4 oacc[32] = {};
    float m_st[4] = {-1e30f, -1e30f, -1e30f, -1e30f};
    float l_st[4] = {0.f, 0.f, 0.f, 0.f};

    for (int kc = 0; kc < NS / 32; kc++) {
        __syncthreads();
#pragma unroll
        for (int i = 0; i < 8; i++) {
            int c = t + i * 256;
            int row = c >> 6, off = (c & 63) * 8;
            *(f16x8*)&Ks[row * 520 + off] =
                *(const f16x8*)(kg + (size_t)(kc * 32 + row) * NE + off);
        }
#pragma unroll
        for (int i = 0; i < 8; i++) {
            int c = t + i * 256;
            int d = c >> 2, off = (c & 3) * 8;
            *(f16x8*)&Vs[d * 40 + off] =
                *(const f16x8*)(vg + (size_t)d * NS + kc * 32 + off);
        }
        __syncthreads();

        f32x4 s0 = {}, s1 = {};
#pragma unroll
        for (int ks = 0; ks < 16; ks++) {
            f16x8 b0v = *(const f16x8*)&Ks[lcol * 520 + ks * 32 + lq * 8];
            f16x8 b1v = *(const f16x8*)&Ks[(16 + lcol) * 520 + ks * 32 + lq * 8];
            s0 = __builtin_amdgcn_mfma_f32_16x16x32_f16(qf[ks], b0v, s0, 0, 0, 0);
            s1 = __builtin_amdgcn_mfma_f32_16x16x32_f16(qf[ks], b1v, s1, 0, 0, 0);
        }

        float alpha[4];
#pragma unroll
        for (int r = 0; r < 4; r++) {
            float vmx = fmaxf(s0[r], s1[r]);
#pragma unroll
            for (int msk = 8; msk; msk >>= 1) vmx = fmaxf(vmx, __shfl_xor(vmx, msk, 64));
            float mn = fmaxf(m_st[r], vmx);
            alpha[r] = __expf(m_st[r] - mn);
            float p0 = __expf(s0[r] - mn);
            float p1 = __expf(s1[r] - mn);
            float sm = p0 + p1;
#pragma unroll
            for (int msk = 8; msk; msk >>= 1) sm += __shfl_xor(sm, msk, 64);
            l_st[r] = l_st[r] * alpha[r] + sm;
            m_st[r] = mn;
            Ps[w][(lq * 4 + r) * 40 + lcol]      = (_Float16)p0;
            Ps[w][(lq * 4 + r) * 40 + 16 + lcol] = (_Float16)p1;
        }
#pragma unroll
        for (int nt = 0; nt < 32; nt++) {
            oacc[nt][0] *= alpha[0]; oacc[nt][1] *= alpha[1];
            oacc[nt][2] *= alpha[2]; oacc[nt][3] *= alpha[3];
        }
        f16x8 pa = *(const f16x8*)&Ps[w][lcol * 40 + lq * 8];
#pragma unroll
        for (int nt = 0; nt < 32; nt++) {
            f16x8 vb = *(const f16x8*)&Vs[(nt * 16 + lcol) * 40 + lq * 8];
            oacc[nt] = __builtin_amdgcn_mfma_f32_16x16x32_f16(pa, vb, oacc[nt], 0, 0, 0);
        }
    }

#pragma unroll
    for (int r = 0; r < 4; r++) {
        const float inv = 1.0f / l_st[r];
        const size_t ob = ((size_t)babs * NS + q0 + w * 16 + lq * 4 + r) * NE + lcol;
#pragma unroll
        for (int nt = 0; nt < 32; nt++)
            out[ob + nt * 16] = oacc[nt][r] * inv;
    }
}

extern "C" void kernel_launch(void* const* d_in, const int* in_sizes, int n_in,
                              void* d_out, int out_size, void* d_ws, size_t ws_size,
                              hipStream_t stream) {
    const float* query = (const float*)d_in[0];
    const float* key_  = (const float*)d_in[1];
    const float* value = (const float*)d_in[2];
    const float* Wq    = (const float*)d_in[3];
    const float* bq    = (const float*)d_in[4];
    const float* Wk    = (const float*)d_in[5];
    const float* bk    = (const float*)d_in[6];
    const float* Wv    = (const float*)d_in[7];
    const float* bv    = (const float*)d_in[8];

    // Q + K + V^T (all f16) live in d_ws, chunked by batch to fit ws_size.
    // Per-batch: 3 * 4096*512 * 2B = 12 MiB.
    const size_t per_batch = (size_t)3 * NS * NE * 2;
    int nb_chunk = (int)(ws_size / per_batch);
    if (nb_chunk > NB) nb_chunk = NB;
    if (nb_chunk < 1)  nb_chunk = 1;

    _Float16* qh  = (_Float16*)d_ws;                        // [nb*S, E]
    _Float16* kh  = qh + (size_t)nb_chunk * NS * NE;        // [nb*S, E]
    _Float16* vth = kh + (size_t)nb_chunk * NS * NE;        // [nb, E, S]

    for (int b0 = 0; b0 < NB; b0 += nb_chunk) {
        int nb = NB - b0 < nb_chunk ? NB - b0 : nb_chunk;
        proj_kernel<<<dim3(nb * 128, 3, 1), 256, 0, stream>>>(
            query, key_, value, Wq, Wk, Wv, bq, bk, bv, qh, kh, vth, b0);
        attn_kernel<<<dim3(NS / 64, nb, 1), 256, 0, stream>>>(
            qh, kh, vth, (float*)d_out, b0);
    }
}

// Round 4
// 826.707 us; speedup vs baseline: 1.0799x; 1.0799x over previous
//
#include <hip/hip_runtime.h>

typedef __attribute__((ext_vector_type(8))) _Float16 f16x8;
typedef __attribute__((ext_vector_type(4))) _Float16 f16x4;
typedef __attribute__((ext_vector_type(4))) float f32x4;

#define NB 4
#define NS 4096
#define NE 512

__device__ __forceinline__ f16x8 cvt2(float4 a, float4 b) {
    f16x8 r;
    r[0] = (_Float16)a.x; r[1] = (_Float16)a.y; r[2] = (_Float16)a.z; r[3] = (_Float16)a.w;
    r[4] = (_Float16)b.x; r[5] = (_Float16)b.y; r[6] = (_Float16)b.z; r[7] = (_Float16)b.w;
    return r;
}

// ---------------- Stage 1: fused QKV projection (fp32 in, f16 out) ------
// (unchanged from round 3 — passed; optimize later)
__global__ __launch_bounds__(256) void proj_kernel(
    const float* __restrict__ Xq, const float* __restrict__ Xk,
    const float* __restrict__ Xv,
    const float* __restrict__ Wq, const float* __restrict__ Wk,
    const float* __restrict__ Wv,
    const float* __restrict__ bq, const float* __restrict__ bk,
    const float* __restrict__ bv,
    _Float16* __restrict__ oq, _Float16* __restrict__ ok,
    _Float16* __restrict__ ovt, int b0)
{
    __shared__ __align__(16) _Float16 As[128 * 32];
    __shared__ __align__(16) _Float16 Bs[128 * 32];
    const int t = threadIdx.x;
    const int w = t >> 6, ln = t & 63;
    const int which = blockIdx.y;
    const float* X    = (which == 0) ? Xq : ((which == 1) ? Xk : Xv);
    const float* W    = (which == 0) ? Wq : ((which == 1) ? Wk : Wv);
    const float* bias = (which == 0) ? bq : ((which == 1) ? bk : bv);

    const int m0 = (blockIdx.x >> 2) * 128;
    const int n0 = (blockIdx.x & 3) * 128;

    const int srow  = t >> 1;
    const int shalf = (t & 1) * 16;
    const float* gA = X + ((size_t)b0 * NS + m0 + srow) * NE + shalf;
    const float* gB = W + (size_t)(n0 + srow) * NE + shalf;
    _Float16* lA = &As[srow * 32 + shalf];
    _Float16* lB = &Bs[srow * 32 + shalf];

    f32x4 acc[4][4] = {};
    const int wm = (w >> 1) * 64, wn = (w & 1) * 64;
    const int lcol = ln & 15, lq = ln >> 4;

    for (int k0 = 0; k0 < NE; k0 += 32) {
        float4 xa0 = *(const float4*)(gA + k0);
        float4 xa1 = *(const float4*)(gA + k0 + 4);
        float4 xa2 = *(const float4*)(gA + k0 + 8);
        float4 xa3 = *(const float4*)(gA + k0 + 12);
        float4 xb0 = *(const float4*)(gB + k0);
        float4 xb1 = *(const float4*)(gB + k0 + 4);
        float4 xb2 = *(const float4*)(gB + k0 + 8);
        float4 xb3 = *(const float4*)(gB + k0 + 12);
        __syncthreads();
        *(f16x8*)lA       = cvt2(xa0, xa1);
        *(f16x8*)(lA + 8) = cvt2(xa2, xa3);
        *(f16x8*)lB       = cvt2(xb0, xb1);
        *(f16x8*)(lB + 8) = cvt2(xb2, xb3);
        __syncthreads();
        f16x8 a[4], b[4];
#pragma unroll
        for (int i = 0; i < 4; i++)
            a[i] = *(const f16x8*)&As[(wm + i * 16 + lcol) * 32 + lq * 8];
#pragma unroll
        for (int j = 0; j < 4; j++)
            b[j] = *(const f16x8*)&Bs[(wn + j * 16 + lcol) * 32 + lq * 8];
#pragma unroll
        for (int i = 0; i < 4; i++)
#pragma unroll
            for (int j = 0; j < 4; j++)
                acc[i][j] = __builtin_amdgcn_mfma_f32_16x16x32_f16(a[i], b[j], acc[i][j], 0, 0, 0);
    }

    if (which < 2) {
        _Float16* o = (which == 0) ? oq : ok;
#pragma unroll
        for (int j = 0; j < 4; j++) {
            const int col = n0 + wn + j * 16 + lcol;
            const float bb = bias[col];
#pragma unroll
            for (int i = 0; i < 4; i++) {
                const int rbase = m0 + wm + i * 16 + lq * 4;
#pragma unroll
                for (int r = 0; r < 4; r++)
                    o[(size_t)(rbase + r) * NE + col] = (_Float16)(acc[i][j][r] + bb);
            }
        }
    } else {
#pragma unroll
        for (int j = 0; j < 4; j++) {
            const int d = n0 + wn + j * 16 + lcol;
            const float bb = bias[d];
#pragma unroll
            for (int i = 0; i < 4; i++) {
                const int rbase = m0 + wm + i * 16 + lq * 4;
                const int bat = rbase >> 12;
                const int s   = rbase & 4095;
                f16x4 pk;
#pragma unroll
                for (int r = 0; r < 4; r++) pk[r] = (_Float16)(acc[i][j][r] + bb);
                *(f16x4*)&ovt[((size_t)bat * NE + d) * NS + s] = pk;
            }
        }
    }
}

// ---------------- Stage 2: flash attention v3 ---------------------------
// 512 threads = 8 waves. Waves 0-3: keys [0,2048); waves 4-7: [2048,4096).
// Wave w owns q-rows (w&3)*16..+16. K staged in LDS per group; V B-frags
// direct from global (rolling 8-reg window); exact merge of the two halves.
__global__ __launch_bounds__(512) void attn_kernel(
    const _Float16* __restrict__ q, const _Float16* __restrict__ k,
    const _Float16* __restrict__ vt, float* __restrict__ out, int b0)
{
    __shared__ __align__(16) unsigned char smem[76800];
    _Float16* Ks      = (_Float16*)smem;              // loop: [2][32*520]
    _Float16* Ps      = (_Float16*)(smem + 66560);    // loop: [8][16*40]
    float*    pairbuf = (float*)smem;                 // combine: [2][8192] f32
    float*    mlbuf   = (float*)(smem + 66560);       // combine: [64][4]

    const int t = threadIdx.x, w = t >> 6, ln = t & 63;
    const int lcol = ln & 15, lq = ln >> 4;
    const int grp = w >> 2, wq = w & 3;
    const int tg = t & 255;
    const int rel = blockIdx.y, babs = b0 + rel;
    const int q0 = blockIdx.x * 64;
    const int koff = grp * 2048;

    // Q A-frags (16 regs of f16x8): row = q0 + wq*16 + lcol
    const _Float16* qp = q + ((size_t)rel * NS + q0 + wq * 16 + lcol) * NE + lq * 8;
    f16x8 qf[16];
#pragma unroll
    for (int ks = 0; ks < 16; ks++) qf[ks] = *(const f16x8*)(qp + ks * 32);

    const _Float16* kgG = k + ((size_t)rel * NS + koff) * NE;
    const _Float16* vbase = vt + ((size_t)rel * NE + lcol) * NS + koff + lq * 8;
    _Float16* KsG = Ks + grp * (32 * 520);
    _Float16* PsW = Ps + w * 640;

    f32x4 oacc[32] = {};
    float m_st[4] = {-1e30f, -1e30f, -1e30f, -1e30f};
    float l_st[4] = {0.f, 0.f, 0.f, 0.f};

    for (int kc = 0; kc < 64; kc++) {
        __syncthreads();
        // stage my group's K chunk: 32 rows x 512 halfs, padded stride 520
#pragma unroll
        for (int i = 0; i < 8; i++) {
            int c = tg + i * 256;
            int row = c >> 6, off = (c & 63) * 8;
            *(f16x8*)&KsG[row * 520 + off] =
                *(const f16x8*)(kgG + (size_t)(kc * 32 + row) * NE + off);
        }
        __syncthreads();

        // V prefetch (first 8 of 32 B-frags) — hidden behind QK+softmax
        const _Float16* vB = vbase + kc * 32;
        f16x8 vb[8];
#pragma unroll
        for (int j = 0; j < 8; j++)
            vb[j] = *(const f16x8*)(vB + (size_t)j * 16 * NS);

        // QK^T: 16 q-rows x 32 keys
        f32x4 s0 = {}, s1 = {};
#pragma unroll
        for (int ks = 0; ks < 16; ks++) {
            f16x8 b0v = *(const f16x8*)&KsG[lcol * 520 + ks * 32 + lq * 8];
            f16x8 b1v = *(const f16x8*)&KsG[(16 + lcol) * 520 + ks * 32 + lq * 8];
            s0 = __builtin_amdgcn_mfma_f32_16x16x32_f16(qf[ks], b0v, s0, 0, 0, 0);
            s1 = __builtin_amdgcn_mfma_f32_16x16x32_f16(qf[ks], b1v, s1, 0, 0, 0);
        }

        float alpha[4];
#pragma unroll
        for (int r = 0; r < 4; r++) {
            float vmx = fmaxf(s0[r], s1[r]);
#pragma unroll
            for (int msk = 8; msk; msk >>= 1) vmx = fmaxf(vmx, __shfl_xor(vmx, msk, 64));
            float mn = fmaxf(m_st[r], vmx);
            alpha[r] = __expf(m_st[r] - mn);
            float p0 = __expf(s0[r] - mn);
            float p1 = __expf(s1[r] - mn);
            float sm = p0 + p1;
#pragma unroll
            for (int msk = 8; msk; msk >>= 1) sm += __shfl_xor(sm, msk, 64);
            l_st[r] = l_st[r] * alpha[r] + sm;
            m_st[r] = mn;
            PsW[(lq * 4 + r) * 40 + lcol]      = (_Float16)p0;
            PsW[(lq * 4 + r) * 40 + 16 + lcol] = (_Float16)p1;
        }
        // skip the 128-mul rescale when m didn't move anywhere in the wave (exact)
        bool allone = (alpha[0] == 1.f) & (alpha[1] == 1.f) &
                      (alpha[2] == 1.f) & (alpha[3] == 1.f);
        if (!__all(allone)) {
#pragma unroll
            for (int nt = 0; nt < 32; nt++) {
                oacc[nt][0] *= alpha[0]; oacc[nt][1] *= alpha[1];
                oacc[nt][2] *= alpha[2]; oacc[nt][3] *= alpha[3];
            }
        }
        // P C->A layout via wave-private LDS
        f16x8 pa = *(const f16x8*)&PsW[lcol * 40 + lq * 8];
        // PV with rolling global V window
#pragma unroll
        for (int nt = 0; nt < 32; nt++) {
            f16x8 cur = vb[nt & 7];
            if (nt < 24) vb[nt & 7] = *(const f16x8*)(vB + (size_t)(nt + 8) * 16 * NS);
            oacc[nt] = __builtin_amdgcn_mfma_f32_16x16x32_f16(pa, cur, oacc[nt], 0, 0, 0);
        }
    }

    // ---- merge the two K-halves (exact online-softmax merge) ----
    __syncthreads();
    const int rowb = wq * 16 + lq * 4;
    if (lcol == 0) {
#pragma unroll
        for (int r = 0; r < 4; r++) {
            mlbuf[(rowb + r) * 4 + grp * 2]     = m_st[r];
            mlbuf[(rowb + r) * 4 + grp * 2 + 1] = l_st[r];
        }
    }
    __syncthreads();
    float bfac[4], linv[4];
#pragma unroll
    for (int r = 0; r < 4; r++) {
        float mo = mlbuf[(rowb + r) * 4 + (1 - grp) * 2];
        float lo = mlbuf[(rowb + r) * 4 + (1 - grp) * 2 + 1];
        float mf = fmaxf(m_st[r], mo);
        bfac[r] = __expf(m_st[r] - mf);
        float lfin = l_st[r] * bfac[r] + lo * __expf(mo - mf);
        linv[r] = 1.0f / lfin;
    }
    // two rounds of pair exchange through reused LDS (2 x 32 KB buffers)
#pragma unroll
    for (int round = 0; round < 2; round++) {
        bool active = ((wq >> 1) == round);
        float* buf = pairbuf + (wq & 1) * 8192;
        if (active && grp == 1) {
#pragma unroll
            for (int nt = 0; nt < 32; nt++) {
                f32x4 vs;
#pragma unroll
                for (int r = 0; r < 4; r++) vs[r] = oacc[nt][r] * bfac[r];
                *(f32x4*)&buf[(nt * 64 + ln) * 4] = vs;
            }
        }
        __syncthreads();
        if (active && grp == 0) {
#pragma unroll
            for (int nt = 0; nt < 32; nt++) {
                f32x4 o1 = *(const f32x4*)&buf[(nt * 64 + ln) * 4];
#pragma unroll
                for (int r = 0; r < 4; r++)
                    oacc[nt][r] = (oacc[nt][r] * bfac[r] + o1[r]) * linv[r];
            }
        }
        __syncthreads();
    }
    if (grp == 0) {
#pragma unroll
        for (int r = 0; r < 4; r++) {
            const size_t ob = ((size_t)babs * NS + q0 + wq * 16 + lq * 4 + r) * NE + lcol;
#pragma unroll
            for (int nt = 0; nt < 32; nt++)
                out[ob + nt * 16] = oacc[nt][r];
        }
    }
}

extern "C" void kernel_launch(void* const* d_in, const int* in_sizes, int n_in,
                              void* d_out, int out_size, void* d_ws, size_t ws_size,
                              hipStream_t stream) {
    const float* query = (const float*)d_in[0];
    const float* key_  = (const float*)d_in[1];
    const float* value = (const float*)d_in[2];
    const float* Wq    = (const float*)d_in[3];
    const float* bq    = (const float*)d_in[4];
    const float* Wk    = (const float*)d_in[5];
    const float* bk    = (const float*)d_in[6];
    const float* Wv    = (const float*)d_in[7];
    const float* bv    = (const float*)d_in[8];

    const size_t per_batch = (size_t)3 * NS * NE * 2;   // q+k+vt f16 = 12 MiB
    int nb_chunk = (int)(ws_size / per_batch);
    if (nb_chunk > NB) nb_chunk = NB;
    if (nb_chunk < 1)  nb_chunk = 1;

    _Float16* qh  = (_Float16*)d_ws;
    _Float16* kh  = qh + (size_t)nb_chunk * NS * NE;
    _Float16* vth = kh + (size_t)nb_chunk * NS * NE;

    for (int b0 = 0; b0 < NB; b0 += nb_chunk) {
        int nb = NB - b0 < nb_chunk ? NB - b0 : nb_chunk;
        proj_kernel<<<dim3(nb * 128, 3, 1), 256, 0, stream>>>(
            query, key_, value, Wq, Wk, Wv, bq, bk, bv, qh, kh, vth, b0);
        attn_kernel<<<dim3(NS / 64, nb, 1), 512, 0, stream>>>(
            qh, kh, vth, (float*)d_out, b0);
    }
}

// Round 5
// 518.119 us; speedup vs baseline: 1.7231x; 1.5956x over previous
//
#include <hip/hip_runtime.h>

typedef __attribute__((ext_vector_type(8))) _Float16 f16x8;
typedef __attribute__((ext_vector_type(4))) _Float16 f16x4;
typedef __attribute__((ext_vector_type(4))) float f32x4;

#define NB 4
#define NS 4096
#define NE 512

__device__ __forceinline__ f16x8 cvt2(float4 a, float4 b) {
    f16x8 r;
    r[0] = (_Float16)a.x; r[1] = (_Float16)a.y; r[2] = (_Float16)a.z; r[3] = (_Float16)a.w;
    r[4] = (_Float16)b.x; r[5] = (_Float16)b.y; r[6] = (_Float16)b.z; r[7] = (_Float16)b.w;
    return r;
}
__device__ __forceinline__ void gload_lds16(const void* g, void* l) {
    __builtin_amdgcn_global_load_lds(
        (const __attribute__((address_space(1))) void*)g,
        (__attribute__((address_space(3))) void*)l, 16, 0, 0);
}

// ---------------- Stage 1: fused QKV projection (fp32 in, f16 out) ------
// q: natural [row][e]. k: swizzled rows — element (s,e) at s*512 + ((e/8)^(s&7))*8 + e%8.
// v: chunked+swizzled [b][kc][e][64]: (d,s) at ((b*64+kc)*512+d)*64 + (((s&63)/8)^(d&7))*8 + s%8.
__global__ __launch_bounds__(256) void proj_kernel(
    const float* __restrict__ Xq, const float* __restrict__ Xk,
    const float* __restrict__ Xv,
    const float* __restrict__ Wq, const float* __restrict__ Wk,
    const float* __restrict__ Wv,
    const float* __restrict__ bq, const float* __restrict__ bk,
    const float* __restrict__ bv,
    _Float16* __restrict__ oq, _Float16* __restrict__ ok,
    _Float16* __restrict__ ovt, int b0)
{
    __shared__ __align__(16) _Float16 As[128 * 32];
    __shared__ __align__(16) _Float16 Bs[128 * 32];
    const int t = threadIdx.x;
    const int w = t >> 6, ln = t & 63;
    const int which = blockIdx.y;
    const float* X    = (which == 0) ? Xq : ((which == 1) ? Xk : Xv);
    const float* W    = (which == 0) ? Wq : ((which == 1) ? Wk : Wv);
    const float* bias = (which == 0) ? bq : ((which == 1) ? bk : bv);

    const int m0 = (blockIdx.x >> 2) * 128;
    const int n0 = (blockIdx.x & 3) * 128;

    const int srow  = t >> 1;
    const int shalf = (t & 1) * 16;
    const float* gA = X + ((size_t)b0 * NS + m0 + srow) * NE + shalf;
    const float* gB = W + (size_t)(n0 + srow) * NE + shalf;
    _Float16* lA = &As[srow * 32 + shalf];
    _Float16* lB = &Bs[srow * 32 + shalf];

    f32x4 acc[4][4] = {};
    const int wm = (w >> 1) * 64, wn = (w & 1) * 64;
    const int lcol = ln & 15, lq = ln >> 4;

    for (int k0 = 0; k0 < NE; k0 += 32) {
        float4 xa0 = *(const float4*)(gA + k0);
        float4 xa1 = *(const float4*)(gA + k0 + 4);
        float4 xa2 = *(const float4*)(gA + k0 + 8);
        float4 xa3 = *(const float4*)(gA + k0 + 12);
        float4 xb0 = *(const float4*)(gB + k0);
        float4 xb1 = *(const float4*)(gB + k0 + 4);
        float4 xb2 = *(const float4*)(gB + k0 + 8);
        float4 xb3 = *(const float4*)(gB + k0 + 12);
        __syncthreads();
        *(f16x8*)lA       = cvt2(xa0, xa1);
        *(f16x8*)(lA + 8) = cvt2(xa2, xa3);
        *(f16x8*)lB       = cvt2(xb0, xb1);
        *(f16x8*)(lB + 8) = cvt2(xb2, xb3);
        __syncthreads();
        f16x8 a[4], b[4];
#pragma unroll
        for (int i = 0; i < 4; i++)
            a[i] = *(const f16x8*)&As[(wm + i * 16 + lcol) * 32 + lq * 8];
#pragma unroll
        for (int j = 0; j < 4; j++)
            b[j] = *(const f16x8*)&Bs[(wn + j * 16 + lcol) * 32 + lq * 8];
#pragma unroll
        for (int i = 0; i < 4; i++)
#pragma unroll
            for (int j = 0; j < 4; j++)
                acc[i][j] = __builtin_amdgcn_mfma_f32_16x16x32_f16(a[i], b[j], acc[i][j], 0, 0, 0);
    }

    // C/D layout: col = lane&15, row = (lane>>4)*4 + reg
    if (which == 0) {
#pragma unroll
        for (int j = 0; j < 4; j++) {
            const int col = n0 + wn + j * 16 + lcol;
            const float bb = bias[col];
#pragma unroll
            for (int i = 0; i < 4; i++) {
                const int rbase = m0 + wm + i * 16 + lq * 4;
#pragma unroll
                for (int r = 0; r < 4; r++)
                    oq[(size_t)(rbase + r) * NE + col] = (_Float16)(acc[i][j][r] + bb);
            }
        }
    } else if (which == 1) {
#pragma unroll
        for (int j = 0; j < 4; j++) {
            const int col = n0 + wn + j * 16 + lcol;
            const int cch = col >> 3, clo = col & 7;
            const float bb = bias[col];
#pragma unroll
            for (int i = 0; i < 4; i++) {
                const int rbase = m0 + wm + i * 16 + lq * 4;
#pragma unroll
                for (int r = 0; r < 4; r++) {
                    const int s = rbase + r;
                    ok[(size_t)s * NE + ((cch ^ (s & 7)) << 3) + clo] =
                        (_Float16)(acc[i][j][r] + bb);
                }
            }
        }
    } else {
#pragma unroll
        for (int j = 0; j < 4; j++) {
            const int d = n0 + wn + j * 16 + lcol;
            const float bb = bias[d];
#pragma unroll
            for (int i = 0; i < 4; i++) {
                const int rbase = m0 + wm + i * 16 + lq * 4;
                const int bat = rbase >> 12;
                const int sl  = rbase & 4095;
                const int kc  = sl >> 6;
                const int slot = ((sl >> 3) & 7) ^ (d & 7);
                f16x4 pk;
#pragma unroll
                for (int r = 0; r < 4; r++) pk[r] = (_Float16)(acc[i][j][r] + bb);
                *(f16x4*)&ovt[(((size_t)bat * 64 + kc) * NE + d) * 64 + slot * 8 + (sl & 7)] = pk;
            }
        }
    }
}

// ---------------- Stage 2: flash attention v5 ---------------------------
// 512 thr = 8 waves; block owns 64 q-rows, full 4096 keys, BK=64 per iter.
// wave w: row-tile rt=w&3 (16 rows); g=w>>2: QK keys [g*32,g*32+32),
// PV E-half [g*256,g*256+256). K,V DMA'd into LDS (ws pre-swizzled).
__global__ __launch_bounds__(512, 2) void attn_kernel(
    const _Float16* __restrict__ q, const _Float16* __restrict__ ksw,
    const _Float16* __restrict__ vsw, float* __restrict__ out, int b0)
{
    __shared__ __align__(16) _Float16 Kbuf[64 * 512];
    __shared__ __align__(16) _Float16 Vbuf[512 * 64];
    __shared__ __align__(16) _Float16 Pb[64 * 72];
    __shared__ float mpart[2][64];
    __shared__ float lpart[2][64];

    const int t = threadIdx.x, w = t >> 6, ln = t & 63;
    const int lcol = ln & 15, lq = ln >> 4;
    const int rt = w & 3, g = w >> 2;
    const int xm = lcol & 7;
    const int rel = blockIdx.y, babs = b0 + rel;
    const int q0 = blockIdx.x * 64;

    const _Float16* qp = q + ((size_t)rel * NS + q0 + rt * 16 + lcol) * NE + lq * 8;
    f16x8 qf[16];
#pragma unroll
    for (int ks = 0; ks < 16; ks++) qf[ks] = *(const f16x8*)(qp + ks * 32);

    const _Float16* kbase = ksw + (size_t)rel * NS * NE;
    const _Float16* vbase = vsw + (size_t)rel * NS * NE;

    f32x4 oacc[16] = {};
    float m_st[4] = {-1e30f, -1e30f, -1e30f, -1e30f};
    float l_st[4] = {0.f, 0.f, 0.f, 0.f};

    for (int kc = 0; kc < 64; kc++) {
        __syncthreads();                                   // B0: prev reads done
        const _Float16* kc_src = kbase + (size_t)kc * 64 * NE;
        const _Float16* vc_src = vbase + (size_t)kc * NE * 64;
#pragma unroll
        for (int i = 0; i < 8; i++) {
            const int blk = i * 8 + w;                     // 1 KB block index
            gload_lds16(kc_src + (size_t)blk * 512 + ln * 8, (_Float16*)Kbuf + blk * 512);
            gload_lds16(vc_src + (size_t)blk * 512 + ln * 8, (_Float16*)Vbuf + blk * 512);
        }
        __syncthreads();                                   // B1: staging visible

        // QK: 16 rows x 32 keys (keys g*32..+32)
        f32x4 s0 = {}, s1 = {};
#pragma unroll
        for (int ks = 0; ks < 16; ks++) {
            const int ch = ((ks * 4 + lq) ^ xm) * 8;
            f16x8 kb0 = *(const f16x8*)&Kbuf[(g * 32 + lcol) * 512 + ch];
            f16x8 kb1 = *(const f16x8*)&Kbuf[(g * 32 + 16 + lcol) * 512 + ch];
            s0 = __builtin_amdgcn_mfma_f32_16x16x32_f16(qf[ks], kb0, s0, 0, 0, 0);
            s1 = __builtin_amdgcn_mfma_f32_16x16x32_f16(qf[ks], kb1, s1, 0, 0, 0);
        }
        // partial row-max over this wave's 32 keys
#pragma unroll
        for (int r = 0; r < 4; r++) {
            float vmx = fmaxf(s0[r], s1[r]);
#pragma unroll
            for (int msk = 8; msk; msk >>= 1) vmx = fmaxf(vmx, __shfl_xor(vmx, msk, 64));
            if (lcol == 0) mpart[g][rt * 16 + lq * 4 + r] = vmx;
        }
        __syncthreads();                                   // B2

        float alpha[4];
#pragma unroll
        for (int r = 0; r < 4; r++) {
            const int row = rt * 16 + lq * 4 + r;
            float mc = fmaxf(mpart[0][row], mpart[1][row]);
            float mn = fmaxf(m_st[r], mc);
            alpha[r] = __expf(m_st[r] - mn);
            float p0 = __expf(s0[r] - mn);
            float p1 = __expf(s1[r] - mn);
            Pb[row * 72 + g * 32 + lcol]      = (_Float16)p0;
            Pb[row * 72 + g * 32 + 16 + lcol] = (_Float16)p1;
            float sm = p0 + p1;
#pragma unroll
            for (int msk = 8; msk; msk >>= 1) sm += __shfl_xor(sm, msk, 64);
            if (lcol == 0) lpart[g][row] = sm;
            m_st[r] = mn;
        }
        __syncthreads();                                   // B3
#pragma unroll
        for (int r = 0; r < 4; r++) {
            const int row = rt * 16 + lq * 4 + r;
            l_st[r] = l_st[r] * alpha[r] + lpart[0][row] + lpart[1][row];
        }
        bool allone = (alpha[0] == 1.f) & (alpha[1] == 1.f) &
                      (alpha[2] == 1.f) & (alpha[3] == 1.f);
        if (!__all(allone)) {
#pragma unroll
            for (int et = 0; et < 16; et++) {
                oacc[et][0] *= alpha[0]; oacc[et][1] *= alpha[1];
                oacc[et][2] *= alpha[2]; oacc[et][3] *= alpha[3];
            }
        }
        // PV: rows rt*16..+16, E-cols g*256..+256, K=64
        f16x8 pa0 = *(const f16x8*)&Pb[(rt * 16 + lcol) * 72 + lq * 8];
        f16x8 pa1 = *(const f16x8*)&Pb[(rt * 16 + lcol) * 72 + 32 + lq * 8];
#pragma unroll
        for (int et = 0; et < 16; et++) {
            const int e = g * 256 + et * 16 + lcol;
            f16x8 v0 = *(const f16x8*)&Vbuf[e * 64 + ((lq ^ xm) * 8)];
            f16x8 v1 = *(const f16x8*)&Vbuf[e * 64 + (((4 + lq) ^ xm) * 8)];
            oacc[et] = __builtin_amdgcn_mfma_f32_16x16x32_f16(pa0, v0, oacc[et], 0, 0, 0);
            oacc[et] = __builtin_amdgcn_mfma_f32_16x16x32_f16(pa1, v1, oacc[et], 0, 0, 0);
        }
    }

#pragma unroll
    for (int r = 0; r < 4; r++) {
        const float inv = 1.0f / l_st[r];
        const size_t ob = ((size_t)babs * NS + q0 + rt * 16 + lq * 4 + r) * NE + g * 256 + lcol;
#pragma unroll
        for (int et = 0; et < 16; et++)
            out[ob + et * 16] = oacc[et][r] * inv;
    }
}

extern "C" void kernel_launch(void* const* d_in, const int* in_sizes, int n_in,
                              void* d_out, int out_size, void* d_ws, size_t ws_size,
                              hipStream_t stream) {
    const float* query = (const float*)d_in[0];
    const float* key_  = (const float*)d_in[1];
    const float* value = (const float*)d_in[2];
    const float* Wq    = (const float*)d_in[3];
    const float* bq    = (const float*)d_in[4];
    const float* Wk    = (const float*)d_in[5];
    const float* bk    = (const float*)d_in[6];
    const float* Wv    = (const float*)d_in[7];
    const float* bv    = (const float*)d_in[8];

    const size_t per_batch = (size_t)3 * NS * NE * 2;   // q + k_sw + v_sw f16 = 12 MiB
    int nb_chunk = (int)(ws_size / per_batch);
    if (nb_chunk > NB) nb_chunk = NB;
    if (nb_chunk < 1)  nb_chunk = 1;

    _Float16* qh  = (_Float16*)d_ws;
    _Float16* kh  = qh + (size_t)nb_chunk * NS * NE;
    _Float16* vth = kh + (size_t)nb_chunk * NS * NE;

    for (int b0 = 0; b0 < NB; b0 += nb_chunk) {
        int nb = NB - b0 < nb_chunk ? NB - b0 : nb_chunk;
        proj_kernel<<<dim3(nb * 128, 3, 1), 256, 0, stream>>>(
            query, key_, value, Wq, Wk, Wv, bq, bk, bv, qh, kh, vth, b0);
        attn_kernel<<<dim3(NS / 64, nb, 1), 512, 0, stream>>>(
            qh, kh, vth, (float*)d_out, b0);
    }
}